// Round 8
// baseline (129.923 us; speedup 1.0000x reference)
//
#include <hip/hip_runtime.h>

// SupConLoss on MI355X. features: [4096, 2, 128] fp32; labels: [4096] int; out: 1 f32.
//
// R7 changes vs R6:
//  - k_negsum: 2-wave (128-thr) blocks over 64-row granules, strips of 4
//    col-granules, K-split 8 KB double buffers (16 KB LDS/block). VGPR-capped
//    16 waves/CU = 8 block-pipelines (vs 4), B LDS-read amplification 4x->2x.
//    Triangular granule grid: 2112 blocks ~= 8/CU exactly.
//  - k_bucket fused into k_normalize (block 0 tail work). 4 launches -> 3.
//  - k_loss unchanged from R6 (verified).
//
// ws layout: nf (2 MB) | neg_sum 8192 f32 | total f32 | done u32 | counts 100
//            | offsets 101 | classIdx 4096

#define BATCH 4096
#define NN    8192
#define DD    128
#define NCLS  100
#define MAXR  192
#define NG    128         // 64-row granules
#define SEG   4           // col-granules per strip
#define NSEG  2112        // sum_{ri=0}^{127} ceil((128-ri)/4)
#define SCALE (1.0f / 0.07f)

typedef __attribute__((ext_vector_type(8))) short bf16x8;
typedef __attribute__((ext_vector_type(4))) float f32x4;

__device__ __forceinline__ unsigned short f2bf(float f) {
    unsigned u = __float_as_uint(f);
    u += 0x7FFF + ((u >> 16) & 1);
    return (unsigned short)(u >> 16);
}

// normalize + zero accumulators; block 0 additionally does class bucketing
__global__ __launch_bounds__(256) void k_normalize(
        const float* __restrict__ feat, unsigned short* __restrict__ nf,
        float* __restrict__ zeroReg, const int* __restrict__ labels,
        int* __restrict__ counts, int* __restrict__ offsets,
        int* __restrict__ classIdx) {
    int gi = blockIdx.x * 256 + threadIdx.x;
    if (gi < NN + 2) zeroReg[gi] = 0.0f;
    int wave = threadIdx.x >> 6, lane = threadIdx.x & 63;
    int row = blockIdx.x * 4 + wave;
    int v = row >> 12, b = row & (BATCH - 1);
    const float2* src = (const float2*)(feat + ((size_t)b * 2 + v) * DD);
    float2 x = src[lane];
    float ss = x.x * x.x + x.y * x.y;
    #pragma unroll
    for (int m = 32; m >= 1; m >>= 1) ss += __shfl_xor(ss, m, 64);
    float inv = rsqrtf(ss);
    ushort2 o;
    o.x = f2bf(x.x * inv);
    o.y = f2bf(x.y * inv);
    ((ushort2*)(nf + (size_t)row * DD))[lane] = o;

    if (blockIdx.x == 0) {   // fused bucketing (independent of other blocks)
        __shared__ int cnt[NCLS], off[NCLS], cur[NCLS];
        int tid = threadIdx.x;
        for (int c = tid; c < NCLS; c += 256) cnt[c] = 0;
        __syncthreads();
        for (int bb = tid; bb < BATCH; bb += 256) atomicAdd(&cnt[labels[bb]], 1);
        __syncthreads();
        if (tid == 0) {
            int a = 0;
            for (int c = 0; c < NCLS; ++c) { off[c] = a; a += cnt[c]; }
        }
        __syncthreads();
        for (int c = tid; c < NCLS; c += 256) {
            cur[c] = 0;
            counts[c] = cnt[c];
            offsets[c] = off[c];
        }
        if (tid == 0) offsets[NCLS] = BATCH;
        __syncthreads();
        for (int bb = tid; bb < BATCH; bb += 256) {
            int l = labels[bb];
            int p = atomicAdd(&cur[l], 1);
            classIdx[off[l] + p] = bb;
        }
    }
}

// ---- pass 1: neg_sum[i] = sum_j exp(logit_ij) [lab(i)!=lab(j)], symmetric ----
// Block = 2 waves (64 rows: granule ri). Strip of up to 4 col-granules; each
// col-granule processed as 2 K-halves (8 KB stage units, XOR mod-8 swizzle).
__global__ __launch_bounds__(128, 4) void k_negsum(
        const unsigned short* __restrict__ nf,
        const int* __restrict__ labels,
        float* __restrict__ neg_sum) {
    __shared__ __attribute__((aligned(16))) unsigned short smem[2 * 4096];  // 16 KB

    // decode triangular strip id -> (ri, cj0, nht)
    int g = blockIdx.x, ri = 0;
    for (;;) {
        int n = (NG - ri + SEG - 1) / SEG;
        if (g < n) break;
        g -= n; ++ri;
    }
    int cj0 = ri + g * SEG;
    int nht = NG - cj0; if (nht > SEG) nht = SEG;
    int nu = nht * 2;                       // stage units (K-halves)

    int tid = threadIdx.x, wave = tid >> 6, lane = tid & 63;
    int q = lane >> 4, nq = lane & 15;
    int rowW = ri * 64 + wave * 32;
    const bf16x8* nfv = (const bf16x8*)nf;

    // A frags: direct global, once per block (full K)
    bf16x8 aF[2][4];
    #pragma unroll
    for (int rs = 0; rs < 2; ++rs) {
        int r = rowW + rs * 16 + nq;
        #pragma unroll
        for (int s = 0; s < 4; ++s) aF[rs][s] = nfv[r * 16 + s * 4 + q];
    }
    int rlab[2][4];
    float rowsum[2][4];
    #pragma unroll
    for (int rs = 0; rs < 2; ++rs)
        #pragma unroll
        for (int rr = 0; rr < 4; ++rr) {
            rlab[rs][rr] = labels[(rowW + rs * 16 + q * 4 + rr) & (BATCH - 1)];
            rowsum[rs][rr] = 0.0f;
        }

    // stage unit u: col-granule cj0+(u>>1), K-half u&1 -> buffer u&1 (8 KB).
    // LDS slot (r, c) holds global chunk (r, kh*8 + (c ^ (r&7))).
    auto stage_u = [&](int u) {
        int cj = cj0 + (u >> 1), kh = u & 1;
        #pragma unroll
        for (int it = 0; it < 4; ++it) {
            int widx = wave * 4 + it;           // 0..7
            int chunkIdx = widx * 64 + lane;    // 0..511
            int r = chunkIdx >> 3, c = chunkIdx & 7;
            int cG = c ^ (r & 7);
            const unsigned short* gp = nf + (size_t)(cj * 64 + r) * DD + kh * 64 + cG * 8;
            unsigned short* lp = smem + (size_t)(u & 1) * 4096 + (size_t)widx * 512;
            __builtin_amdgcn_global_load_lds(
                (const __attribute__((address_space(1))) void*)gp,
                (__attribute__((address_space(3))) void*)lp, 16, 0, 0);
        }
    };

    stage_u(0);
    f32x4 acc[2][4];
    for (int u = 0; u < nu; ++u) {
        __syncthreads();                        // buffer u&1 ready
        if (u + 1 < nu) stage_u(u + 1);
        int kh = u & 1, cj = cj0 + (u >> 1);
        const char* sB = (const char*)(smem + (size_t)(u & 1) * 4096);

        if (kh == 0) {
            #pragma unroll
            for (int rs = 0; rs < 2; ++rs)
                #pragma unroll
                for (int cs = 0; cs < 4; ++cs) acc[rs][cs] = (f32x4){0.f, 0.f, 0.f, 0.f};
        }
        #pragma unroll
        for (int sp = 0; sp < 2; ++sp) {
            bf16x8 bF[4];
            #pragma unroll
            for (int cs = 0; cs < 4; ++cs) {
                int rB = cs * 16 + nq;                     // local row 0..63
                int slot = rB * 8 + ((sp * 4 + q) ^ (nq & 7));
                bF[cs] = *(const bf16x8*)(sB + slot * 16);
            }
            #pragma unroll
            for (int rs = 0; rs < 2; ++rs)
                #pragma unroll
                for (int cs = 0; cs < 4; ++cs)
                    acc[rs][cs] = __builtin_amdgcn_mfma_f32_16x16x32_bf16(
                        aF[rs][kh * 2 + sp], bF[cs], acc[rs][cs], 0, 0, 0);
        }

        if (kh == 1) {                          // half-tile complete: epilogue
            bool diag = (cj == ri);
            int colBase = cj * 64;
            // C/D layout: col = lane&15, row = (lane>>4)*4 + reg
            #pragma unroll
            for (int cs = 0; cs < 4; ++cs) {
                int col = colBase + cs * 16 + nq;
                int cl = labels[col & (BATCH - 1)];
                float colsum = 0.0f;
                #pragma unroll
                for (int rs = 0; rs < 2; ++rs)
                    #pragma unroll
                    for (int rr = 0; rr < 4; ++rr) {
                        float e = __expf(acc[rs][cs][rr] * SCALE);
                        float ev = (rlab[rs][rr] != cl) ? e : 0.0f;
                        rowsum[rs][rr] += ev;
                        colsum += ev;
                    }
                if (!diag) {
                    colsum += __shfl_xor(colsum, 16, 64);
                    colsum += __shfl_xor(colsum, 32, 64);
                    if (q == 0) atomicAdd(&neg_sum[col], colsum);
                }
            }
        }
    }

    #pragma unroll
    for (int rs = 0; rs < 2; ++rs)
        #pragma unroll
        for (int rr = 0; rr < 4; ++rr) {
            float vsum = rowsum[rs][rr];
            vsum += __shfl_xor(vsum, 1, 64);
            vsum += __shfl_xor(vsum, 2, 64);
            vsum += __shfl_xor(vsum, 4, 64);
            vsum += __shfl_xor(vsum, 8, 64);
            if (nq == 0) atomicAdd(&neg_sum[rowW + rs * 16 + q * 4 + rr], vsum);
        }
}

// ---- pass 2: per-class MFMA over member rows + fused finalize ----
__global__ __launch_bounds__(256) void k_loss(
        const unsigned short* __restrict__ nf,
        const int* __restrict__ counts, const int* __restrict__ offsets,
        const int* __restrict__ classIdx,
        const float* __restrict__ neg_sum,
        float* __restrict__ total, unsigned* __restrict__ done,
        float* __restrict__ out) {
    __shared__ __attribute__((aligned(16))) unsigned short s_feat[MAXR * 128]; // 48 KB
    __shared__ int s_rows[MAXR];
    __shared__ float s_ns[MAXR];
    __shared__ float red[4];

    int c = blockIdx.x;
    int m = counts[c], off = offsets[c];
    int twoM = 2 * m; if (twoM > MAXR) twoM = MAXR;
    int tid = threadIdx.x, wave = tid >> 6, lane = tid & 63;
    int q = lane >> 4, nq = lane & 15;

    for (int r = tid; r < twoM; r += 256) {
        int b = classIdx[off + (r < m ? r : r - m)];
        int row = (r < m) ? b : b + BATCH;
        s_rows[r] = row;
        s_ns[r] = neg_sum[row];
    }
    __syncthreads();

    int ntile = (twoM + 63) >> 6;            // 1..3
    int nchunk = ntile * 64 * 16;
    for (int widx = wave; widx * 64 < nchunk; widx += 4) {
        int chunkIdx = widx * 64 + lane;
        int r = chunkIdx >> 4, cS = chunkIdx & 15;
        int cG = cS ^ (r & 15);
        int rc = r < twoM ? r : twoM - 1;
        const unsigned short* gp = nf + (size_t)s_rows[rc] * DD + cG * 8;
        unsigned short* lp = s_feat + (size_t)widx * 512;
        __builtin_amdgcn_global_load_lds(
            (const __attribute__((address_space(1))) void*)gp,
            (__attribute__((address_space(3))) void*)lp, 16, 0, 0);
    }
    __syncthreads();

    const char* sB = (const char*)s_feat;
    float partial = 0.0f;
    int npairs = ntile * ntile;
    for (int pp = wave; pp < npairs; pp += 4) {
        int ti = pp / ntile, tj = pp - ti * ntile;
        bf16x8 aF[4][4];
        #pragma unroll
        for (int rs = 0; rs < 4; ++rs) {
            int rA = ti * 64 + rs * 16 + nq;
            #pragma unroll
            for (int s = 0; s < 4; ++s) {
                int slot = rA * 16 + ((s * 4 + q) ^ nq);
                aF[rs][s] = *(const bf16x8*)(sB + slot * 16);
            }
        }
        f32x4 acc[4][4];
        #pragma unroll
        for (int rs = 0; rs < 4; ++rs)
            #pragma unroll
            for (int cs = 0; cs < 4; ++cs) acc[rs][cs] = (f32x4){0.f, 0.f, 0.f, 0.f};
        #pragma unroll
        for (int s = 0; s < 4; ++s) {
            bf16x8 bF[4];
            #pragma unroll
            for (int cs = 0; cs < 4; ++cs) {
                int rB = tj * 64 + cs * 16 + nq;
                int slot = rB * 16 + ((s * 4 + q) ^ nq);
                bF[cs] = *(const bf16x8*)(sB + slot * 16);
            }
            #pragma unroll
            for (int rs = 0; rs < 4; ++rs)
                #pragma unroll
                for (int cs = 0; cs < 4; ++cs)
                    acc[rs][cs] = __builtin_amdgcn_mfma_f32_16x16x32_bf16(
                        aF[rs][s], bF[cs], acc[rs][cs], 0, 0, 0);
        }
        #pragma unroll
        for (int cs = 0; cs < 4; ++cs) {
            int qq = tj * 64 + cs * 16 + nq;
            float ns = s_ns[qq < twoM ? qq : 0];
            #pragma unroll
            for (int rs = 0; rs < 4; ++rs)
                #pragma unroll
                for (int rr = 0; rr < 4; ++rr) {
                    int p = ti * 64 + rs * 16 + q * 4 + rr;
                    bool valid = (p < twoM) && (qq < twoM) && (p != qq);
                    float logit = acc[rs][cs][rr] * SCALE;
                    float term = logit - __logf(ns + __expf(logit));
                    partial += valid ? term : 0.0f;
                }
        }
    }
    #pragma unroll
    for (int mm = 32; mm >= 1; mm >>= 1) partial += __shfl_xor(partial, mm, 64);
    if (lane == 0) red[wave] = partial;
    __syncthreads();
    if (tid == 0) {
        atomicAdd(total, red[0] + red[1] + red[2] + red[3]);
        __threadfence();
        unsigned prev = __hip_atomic_fetch_add(done, 1u, __ATOMIC_ACQ_REL,
                                               __HIP_MEMORY_SCOPE_AGENT);
        if (prev == (unsigned)(NCLS - 1)) {
            float tot = __hip_atomic_load(total, __ATOMIC_ACQUIRE,
                                          __HIP_MEMORY_SCOPE_AGENT);
            out[0] = -tot * (1.0f / (float)NN);
        }
    }
}

extern "C" void kernel_launch(void* const* d_in, const int* in_sizes, int n_in,
                              void* d_out, int out_size, void* d_ws, size_t ws_size,
                              hipStream_t stream) {
    const float* feat = (const float*)d_in[0];
    const int* labels = (const int*)d_in[1];
    unsigned short* nf = (unsigned short*)d_ws;
    float* neg_sum = (float*)((char*)d_ws + (size_t)NN * DD * sizeof(unsigned short));
    float* total    = neg_sum + NN;           // 1
    unsigned* done  = (unsigned*)(total + 1); // 1
    int* counts     = (int*)(done + 1);       // 100
    int* offsets    = counts + NCLS;          // 101
    int* classIdx   = offsets + NCLS + 1;     // 4096
    float* out = (float*)d_out;

    hipLaunchKernelGGL(k_normalize, dim3(NN / 4), dim3(256), 0, stream,
                       feat, nf, neg_sum, labels, counts, offsets, classIdx);
    hipLaunchKernelGGL(k_negsum, dim3(NSEG), dim3(128), 0, stream, nf, labels, neg_sum);
    hipLaunchKernelGGL(k_loss, dim3(NCLS), dim3(256), 0, stream,
                       nf, counts, offsets, classIdx, neg_sum, total, done, out);
}

// Round 9
// 105.469 us; speedup vs baseline: 1.2319x; 1.2319x over previous
//
#include <hip/hip_runtime.h>

// SupConLoss on MI355X. features: [4096, 2, 128] fp32; labels: [4096] int; out: 1 f32.
//
// R8 changes vs R7:
//  - k_negsum: symmetry ABANDONED — R7 counters showed the col-sum atomics
//    (1.2M device-scope RMWs) generate ~120 MB of HBM coherence traffic
//    (FETCH 80 MB / WRITE 40 MB), dwarfing the 2x FLOP saving. Now: full
//    matrix, grid 64 row-tiles x 16 col-strips (512 cols) = 1024 blocks
//    (4/CU exact). Row sums are block-private registers across the strip;
//    one atomic per row per block (131K total). Staging/frags identical to
//    verified R6 code (16 KB half-tile units, mod-16 XOR swizzle, 2x16 KB
//    double buffer).
//  - k_normalize (fused bucket) and k_loss unchanged from R7 (verified).
//
// ws layout: nf (2 MB) | neg_sum 8192 f32 | total f32 | done u32 | counts 100
//            | offsets 101 | classIdx 4096

#define BATCH 4096
#define NN    8192
#define DD    128
#define NCLS  100
#define MAXR  192
#define SCALE (1.0f / 0.07f)

typedef __attribute__((ext_vector_type(8))) short bf16x8;
typedef __attribute__((ext_vector_type(4))) float f32x4;

__device__ __forceinline__ unsigned short f2bf(float f) {
    unsigned u = __float_as_uint(f);
    u += 0x7FFF + ((u >> 16) & 1);
    return (unsigned short)(u >> 16);
}

// normalize + zero accumulators; block 0 additionally does class bucketing
__global__ __launch_bounds__(256) void k_normalize(
        const float* __restrict__ feat, unsigned short* __restrict__ nf,
        float* __restrict__ zeroReg, const int* __restrict__ labels,
        int* __restrict__ counts, int* __restrict__ offsets,
        int* __restrict__ classIdx) {
    int gi = blockIdx.x * 256 + threadIdx.x;
    if (gi < NN + 2) zeroReg[gi] = 0.0f;
    int wave = threadIdx.x >> 6, lane = threadIdx.x & 63;
    int row = blockIdx.x * 4 + wave;
    int v = row >> 12, b = row & (BATCH - 1);
    const float2* src = (const float2*)(feat + ((size_t)b * 2 + v) * DD);
    float2 x = src[lane];
    float ss = x.x * x.x + x.y * x.y;
    #pragma unroll
    for (int m = 32; m >= 1; m >>= 1) ss += __shfl_xor(ss, m, 64);
    float inv = rsqrtf(ss);
    ushort2 o;
    o.x = f2bf(x.x * inv);
    o.y = f2bf(x.y * inv);
    ((ushort2*)(nf + (size_t)row * DD))[lane] = o;

    if (blockIdx.x == 0) {   // fused bucketing (independent of other blocks)
        __shared__ int cnt[NCLS], off[NCLS], cur[NCLS];
        int tid = threadIdx.x;
        for (int c = tid; c < NCLS; c += 256) cnt[c] = 0;
        __syncthreads();
        for (int bb = tid; bb < BATCH; bb += 256) atomicAdd(&cnt[labels[bb]], 1);
        __syncthreads();
        if (tid == 0) {
            int a = 0;
            for (int c = 0; c < NCLS; ++c) { off[c] = a; a += cnt[c]; }
        }
        __syncthreads();
        for (int c = tid; c < NCLS; c += 256) {
            cur[c] = 0;
            counts[c] = cnt[c];
            offsets[c] = off[c];
        }
        if (tid == 0) offsets[NCLS] = BATCH;
        __syncthreads();
        for (int bb = tid; bb < BATCH; bb += 256) {
            int l = labels[bb];
            int p = atomicAdd(&cur[l], 1);
            classIdx[off[l] + p] = bb;
        }
    }
}

// stage one 64-row x 128-K bf16 half-tile of B (= 64 output cols) into LDS
// buffer `buf` (16 KB); XOR-swizzled: LDS slot (r, cS) = global chunk (r, cS^(r&15)).
__device__ __forceinline__ void stage_half(unsigned short* smem, const unsigned short* nf,
                                           int buf, int hrow, int wave, int lane) {
    #pragma unroll
    for (int it = 0; it < 4; ++it) {
        int widx = wave * 4 + it;              // 0..15
        int chunkIdx = widx * 64 + lane;       // 0..1023
        int r = chunkIdx >> 4, cS = chunkIdx & 15;
        int cG = cS ^ (r & 15);
        const unsigned short* gp = nf + (size_t)(hrow + r) * DD + cG * 8;
        unsigned short* lp = smem + (size_t)buf * 8192 + (size_t)widx * 512;
        __builtin_amdgcn_global_load_lds(
            (const __attribute__((address_space(1))) void*)gp,
            (__attribute__((address_space(3))) void*)lp, 16, 0, 0);
    }
}

// ---- pass 1: neg_sum[i] = sum_j exp(logit_ij) [lab(i)!=lab(j)], full matrix ----
// Block = 4 waves x 32 rows = 128 rows; strip of 512 cols (8 x 64-col units).
// Row sums block-private in registers; ONE atomic per row per block.
__global__ __launch_bounds__(256, 4) void k_negsum(
        const unsigned short* __restrict__ nf,
        const int* __restrict__ labels,
        float* __restrict__ neg_sum) {
    __shared__ __attribute__((aligned(16))) unsigned short smem[2 * 8192];  // 32 KB

    int rowBase = blockIdx.x * 128;
    int colBase = blockIdx.y * 512;

    int tid = threadIdx.x, wave = tid >> 6, lane = tid & 63;
    int q = lane >> 4, nq = lane & 15;
    int rowW = rowBase + wave * 32;            // wave's 32-row base
    const bf16x8* nfv = (const bf16x8*)nf;

    // A frags: direct global (L2-resident), once per block
    bf16x8 aF[2][4];
    #pragma unroll
    for (int rs = 0; rs < 2; ++rs) {
        int r = rowW + rs * 16 + nq;
        #pragma unroll
        for (int s = 0; s < 4; ++s) aF[rs][s] = nfv[r * 16 + s * 4 + q];
    }
    int rlab[2][4];
    float rowsum[2][4];
    #pragma unroll
    for (int rs = 0; rs < 2; ++rs)
        #pragma unroll
        for (int rr = 0; rr < 4; ++rr) {
            rlab[rs][rr] = labels[(rowW + rs * 16 + q * 4 + rr) & (BATCH - 1)];
            rowsum[rs][rr] = 0.0f;
        }

    stage_half(smem, nf, 0, colBase, wave, lane);

    for (int u = 0; u < 8; ++u) {
        __syncthreads();                       // buffer u&1 ready
        if (u + 1 < 8) stage_half(smem, nf, (u + 1) & 1, colBase + (u + 1) * 64, wave, lane);
        const char* sB = (const char*)(smem + (size_t)(u & 1) * 8192);

        f32x4 acc[2][4];
        #pragma unroll
        for (int rs = 0; rs < 2; ++rs)
            #pragma unroll
            for (int cs = 0; cs < 4; ++cs) acc[rs][cs] = (f32x4){0.f, 0.f, 0.f, 0.f};
        #pragma unroll
        for (int s = 0; s < 4; ++s) {
            bf16x8 bF[4];
            #pragma unroll
            for (int cs = 0; cs < 4; ++cs) {
                int rB = cs * 16 + nq;                     // local col-row 0..63
                int slot = rB * 16 + ((s * 4 + q) ^ nq);
                bF[cs] = *(const bf16x8*)(sB + slot * 16);
            }
            #pragma unroll
            for (int rs = 0; rs < 2; ++rs)
                #pragma unroll
                for (int cs = 0; cs < 4; ++cs)
                    acc[rs][cs] = __builtin_amdgcn_mfma_f32_16x16x32_bf16(
                        aF[rs][s], bF[cs], acc[rs][cs], 0, 0, 0);
        }

        int colU = colBase + u * 64;
        // C/D layout: col = lane&15, row = (lane>>4)*4 + reg
        #pragma unroll
        for (int cs = 0; cs < 4; ++cs) {
            int col = colU + cs * 16 + nq;
            int cl = labels[col & (BATCH - 1)];
            #pragma unroll
            for (int rs = 0; rs < 2; ++rs)
                #pragma unroll
                for (int rr = 0; rr < 4; ++rr) {
                    float e = __expf(acc[rs][cs][rr] * SCALE);
                    rowsum[rs][rr] += (rlab[rs][rr] != cl) ? e : 0.0f;
                }
        }
    }

    // reduce across the 16 col-lanes; one atomic per row per block
    #pragma unroll
    for (int rs = 0; rs < 2; ++rs)
        #pragma unroll
        for (int rr = 0; rr < 4; ++rr) {
            float vsum = rowsum[rs][rr];
            vsum += __shfl_xor(vsum, 1, 64);
            vsum += __shfl_xor(vsum, 2, 64);
            vsum += __shfl_xor(vsum, 4, 64);
            vsum += __shfl_xor(vsum, 8, 64);
            if (nq == 0) atomicAdd(&neg_sum[rowW + rs * 16 + q * 4 + rr], vsum);
        }
}

// ---- pass 2: per-class MFMA over member rows + fused finalize ----
__global__ __launch_bounds__(256) void k_loss(
        const unsigned short* __restrict__ nf,
        const int* __restrict__ counts, const int* __restrict__ offsets,
        const int* __restrict__ classIdx,
        const float* __restrict__ neg_sum,
        float* __restrict__ total, unsigned* __restrict__ done,
        float* __restrict__ out) {
    __shared__ __attribute__((aligned(16))) unsigned short s_feat[MAXR * 128]; // 48 KB
    __shared__ int s_rows[MAXR];
    __shared__ float s_ns[MAXR];
    __shared__ float red[4];

    int c = blockIdx.x;
    int m = counts[c], off = offsets[c];
    int twoM = 2 * m; if (twoM > MAXR) twoM = MAXR;
    int tid = threadIdx.x, wave = tid >> 6, lane = tid & 63;
    int q = lane >> 4, nq = lane & 15;

    for (int r = tid; r < twoM; r += 256) {
        int b = classIdx[off + (r < m ? r : r - m)];
        int row = (r < m) ? b : b + BATCH;
        s_rows[r] = row;
        s_ns[r] = neg_sum[row];
    }
    __syncthreads();

    int ntile = (twoM + 63) >> 6;            // 1..3
    int nchunk = ntile * 64 * 16;
    for (int widx = wave; widx * 64 < nchunk; widx += 4) {
        int chunkIdx = widx * 64 + lane;
        int r = chunkIdx >> 4, cS = chunkIdx & 15;
        int cG = cS ^ (r & 15);
        int rc = r < twoM ? r : twoM - 1;
        const unsigned short* gp = nf + (size_t)s_rows[rc] * DD + cG * 8;
        unsigned short* lp = s_feat + (size_t)widx * 512;
        __builtin_amdgcn_global_load_lds(
            (const __attribute__((address_space(1))) void*)gp,
            (__attribute__((address_space(3))) void*)lp, 16, 0, 0);
    }
    __syncthreads();

    const char* sB = (const char*)s_feat;
    float partial = 0.0f;
    int npairs = ntile * ntile;
    for (int pp = wave; pp < npairs; pp += 4) {
        int ti = pp / ntile, tj = pp - ti * ntile;
        bf16x8 aF[4][4];
        #pragma unroll
        for (int rs = 0; rs < 4; ++rs) {
            int rA = ti * 64 + rs * 16 + nq;
            #pragma unroll
            for (int s = 0; s < 4; ++s) {
                int slot = rA * 16 + ((s * 4 + q) ^ nq);
                aF[rs][s] = *(const bf16x8*)(sB + slot * 16);
            }
        }
        f32x4 acc[4][4];
        #pragma unroll
        for (int rs = 0; rs < 4; ++rs)
            #pragma unroll
            for (int cs = 0; cs < 4; ++cs) acc[rs][cs] = (f32x4){0.f, 0.f, 0.f, 0.f};
        #pragma unroll
        for (int s = 0; s < 4; ++s) {
            bf16x8 bF[4];
            #pragma unroll
            for (int cs = 0; cs < 4; ++cs) {
                int rB = tj * 64 + cs * 16 + nq;
                int slot = rB * 16 + ((s * 4 + q) ^ nq);
                bF[cs] = *(const bf16x8*)(sB + slot * 16);
            }
            #pragma unroll
            for (int rs = 0; rs < 4; ++rs)
                #pragma unroll
                for (int cs = 0; cs < 4; ++cs)
                    acc[rs][cs] = __builtin_amdgcn_mfma_f32_16x16x32_bf16(
                        aF[rs][s], bF[cs], acc[rs][cs], 0, 0, 0);
        }
        #pragma unroll
        for (int cs = 0; cs < 4; ++cs) {
            int qq = tj * 64 + cs * 16 + nq;
            float ns = s_ns[qq < twoM ? qq : 0];
            #pragma unroll
            for (int rs = 0; rs < 4; ++rs)
                #pragma unroll
                for (int rr = 0; rr < 4; ++rr) {
                    int p = ti * 64 + rs * 16 + q * 4 + rr;
                    bool valid = (p < twoM) && (qq < twoM) && (p != qq);
                    float logit = acc[rs][cs][rr] * SCALE;
                    float term = logit - __logf(ns + __expf(logit));
                    partial += valid ? term : 0.0f;
                }
        }
    }
    #pragma unroll
    for (int mm = 32; mm >= 1; mm >>= 1) partial += __shfl_xor(partial, mm, 64);
    if (lane == 0) red[wave] = partial;
    __syncthreads();
    if (tid == 0) {
        atomicAdd(total, red[0] + red[1] + red[2] + red[3]);
        __threadfence();
        unsigned prev = __hip_atomic_fetch_add(done, 1u, __ATOMIC_ACQ_REL,
                                               __HIP_MEMORY_SCOPE_AGENT);
        if (prev == (unsigned)(NCLS - 1)) {
            float tot = __hip_atomic_load(total, __ATOMIC_ACQUIRE,
                                          __HIP_MEMORY_SCOPE_AGENT);
            out[0] = -tot * (1.0f / (float)NN);
        }
    }
}

extern "C" void kernel_launch(void* const* d_in, const int* in_sizes, int n_in,
                              void* d_out, int out_size, void* d_ws, size_t ws_size,
                              hipStream_t stream) {
    const float* feat = (const float*)d_in[0];
    const int* labels = (const int*)d_in[1];
    unsigned short* nf = (unsigned short*)d_ws;
    float* neg_sum = (float*)((char*)d_ws + (size_t)NN * DD * sizeof(unsigned short));
    float* total    = neg_sum + NN;           // 1
    unsigned* done  = (unsigned*)(total + 1); // 1
    int* counts     = (int*)(done + 1);       // 100
    int* offsets    = counts + NCLS;          // 101
    int* classIdx   = offsets + NCLS + 1;     // 4096
    float* out = (float*)d_out;

    hipLaunchKernelGGL(k_normalize, dim3(NN / 4), dim3(256), 0, stream,
                       feat, nf, neg_sum, labels, counts, offsets, classIdx);
    hipLaunchKernelGGL(k_negsum, dim3(64, 16), dim3(256), 0, stream, nf, labels, neg_sum);
    hipLaunchKernelGGL(k_loss, dim3(NCLS), dim3(256), 0, stream,
                       nf, counts, offsets, classIdx, neg_sum, total, done, out);
}